// Round 13
// baseline (87.130 us; speedup 1.0000x reference)
//
#include <hip/hip_runtime.h>
#include <hip/hip_bf16.h>

#define Bn 128
#define Nn 8192
#define Hn 128
#define RPB 128
#define JOUT 126
#define NBJ 66    // ceil(8192/126)

typedef __attribute__((ext_vector_type(8))) short short8;
typedef __attribute__((ext_vector_type(4))) float f32x4;
typedef __attribute__((ext_vector_type(4))) unsigned int u32x4;

__device__ __forceinline__ unsigned short f2bf(float x) {
    union { float f; unsigned u; } v; v.f = x;
    return (unsigned short)((v.u + 0x7fffu + ((v.u >> 16) & 1u)) >> 16);
}
__device__ __forceinline__ float bf2f(unsigned short h) {
    union { unsigned u; float f; } v; v.u = ((unsigned)h) << 16;
    return v.f;
}
__device__ __forceinline__ unsigned short flo(float x) {   // low bf16 correction
    return f2bf(x - bf2f(f2bf(x)));
}
__device__ __forceinline__ float asf(unsigned u) {
    union { unsigned u; float f; } v; v.u = u; return v.f;
}
__device__ __forceinline__ float swish(float x) {
    return x * __builtin_amdgcn_rcpf(1.0f + __expf(-x));
}
// HW packed bf16 convert (RNE): dst.lo=cvt(a), dst.hi=cvt(b).
// hip_bf16.h's __float2bfloat16 is a ~5-op software RNE sequence; no builtin
// exists for v_cvt_pk_bf16_f32 on gfx950 (m240) -> inline asm.
__device__ __forceinline__ unsigned pk2(float a, float b) {
    unsigned r;
    asm("v_cvt_pk_bf16_f32 %0, %1, %2" : "=v"(r) : "v"(a), "v"(b));
    return r;
}

// ws (unsigned short, 22528 elems = 45056 B):
//  [0      .. 4095 ]  8  A1-frags (W1 hi/lo + b1 folded), frag mt: m=16mt+(l&15)
//  [4096   .. 20479] 32  A2-frags (W2, k-map kappa), frag (mt2*4+ks)
//  [20480  .. 22527]  4  B3-frags (W3, k-map kappa), frag ks
// kappa(ks, p) = 16*(2ks + ((p&7)>>2)) + 4*(p>>3) + (p&3),  p = slot (l>>4)*8+e
__global__ void prep_kernel(const float* __restrict__ W1, const float* __restrict__ b1,
                            const float* __restrict__ W2, const float* __restrict__ W3,
                            unsigned short* __restrict__ ws)
{
    int tid = blockIdx.x * 256 + threadIdx.x;
    if (tid >= 22528) return;
    int f = tid >> 9, r = tid & 511;
    int l = r >> 3, e = r & 7;
    int p = ((l >> 4) << 3) | e;
    int c16 = l & 15;
    unsigned short v = 0;
    if (f < 8) {
        int col = (f << 4) | c16;
        if (p < 9)        v = f2bf(W1[p * Hn + col]);        // pairs t_hi
        else if (p < 18)  v = flo(W1[(p - 9) * Hn + col]);   // pairs t_hi
        else if (p < 27)  v = f2bf(W1[(p - 18) * Hn + col]); // pairs t_lo
        else if (p == 27) v = f2bf(b1[col]);                 // pairs 1.0
        else if (p == 28) v = flo(b1[col]);                  // pairs 1.0
    } else if (f < 40) {
        int mt2 = (f - 8) >> 2, ks = (f - 8) & 3;
        int col = (mt2 << 4) | c16;
        int k = 16 * (2 * ks + ((p & 7) >> 2)) + ((p >> 3) << 2) + (p & 3);
        v = f2bf(W2[k * Hn + col]);
    } else {
        int ks = f - 40;
        int k = 16 * (2 * ks + ((p & 7) >> 2)) + ((p >> 3) << 2) + (p & 3);
        if (c16 < 9) v = f2bf(W3[k * 9 + c16]);
    }
    ws[tid] = v;
}

__global__ __launch_bounds__(256, 6) void fused_kernel(
    const float* __restrict__ y, const float* __restrict__ b2g,
    const float* __restrict__ b3, const unsigned short* __restrict__ ws,
    float* __restrict__ out)
{
    __shared__ __align__(16) char tb[RPB * 80];  // per-row 32-slot bf16 k-vector, stride 80B
    __shared__ float f_lds[RPB][12];

    const int tid = threadIdx.x;
    const int lane = tid & 63;
    const int w = tid >> 6;
    const int b = blockIdx.y;
    const int j0 = blockIdx.x * JOUT;
    const int r15 = lane & 15, g = lane >> 4;

    const short8* wsf = (const short8*)ws;

    // ---- triplet features: 128 threads, one row each -> hi/lo k-vectors in LDS ----
    if (tid < RPB) {
        int i = j0 - 2 + tid;
        i = (i < 0) ? 0 : ((i > Nn - 3) ? (Nn - 3) : i);
        const float* base = y + ((size_t)b * Nn + i) * 6;
        float xp0 = base[0],  xp1 = base[1],  xp2 = base[2];
        float xm0 = base[6],  xm1 = base[7],  xm2 = base[8];
        float xn0 = base[12], xn1 = base[13], xn2 = base[14];
        float off = atan2f(xm1 - xp1, xm0 - xp0);
        float t0 = xp2 - off, t1 = xm2 - off, t2 = xn2 - off;
        unsigned hw0 = pk2(t0, t1);          // (h0,h1)
        unsigned hw1 = pk2(t2, xp0);         // (h2,h3)
        unsigned hw2 = pk2(xp1, xm0);        // (h4,h5)
        unsigned hw3 = pk2(xm1, xn0);        // (h6,h7)
        unsigned hw8 = pk2(xn1, 1.0f);       // (h8, 1.0)
        float r0 = t0  - asf(hw0 << 16), r1 = t1  - asf(hw0 & 0xffff0000u);
        float r2 = t2  - asf(hw1 << 16), r3 = xp0 - asf(hw1 & 0xffff0000u);
        float r4 = xp1 - asf(hw2 << 16), r5 = xm0 - asf(hw2 & 0xffff0000u);
        float r6 = xm1 - asf(hw3 << 16), r7 = xn0 - asf(hw3 & 0xffff0000u);
        float r8 = xn1 - asf(hw8 << 16);
        u32x4 v0 = { hw0, hw1, hw2, hw3 };                                  // slots 0..7
        u32x4 v1 = { (hw0 << 16) | (hw8 & 0xffffu),                         // (h8,h0)
                     __builtin_amdgcn_alignbit(hw1, hw0, 16),               // (h1,h2)
                     __builtin_amdgcn_alignbit(hw2, hw1, 16),               // (h3,h4)
                     __builtin_amdgcn_alignbit(hw3, hw2, 16) };             // (h5,h6)
        u32x4 v2 = { __builtin_amdgcn_alignbit(hw8, hw3, 16),               // (h7,h8)
                     pk2(r0, r1), pk2(r2, r3), pk2(r4, r5) };               // (l0..l5)
        u32x4 v3 = { pk2(r6, r7), pk2(r8, 1.0f), 0x00003F80u, 0u };        // (l6..l8,1,1,0,0)
        char* dst = tb + tid * 80;
        *(u32x4*)(dst)      = v0;
        *(u32x4*)(dst + 16) = v1;
        *(u32x4*)(dst + 32) = v2;
        *(u32x4*)(dst + 48) = v3;
    }
    __syncthreads();

    // ---- layer 1: per row-tile nt, 8 MFMAs (A=W1 frags, B=t k-vec), hi/lo fp32 ----
    short8 b2f[2][4];
    {
        short8 w1f[8];
        #pragma unroll
        for (int mt = 0; mt < 8; ++mt) w1f[mt] = wsf[mt * 64 + lane];
        #pragma unroll
        for (int nt = 0; nt < 2; ++nt) {
            short8 tf = *(const short8*)(tb + (32 * w + 16 * nt + r15) * 80 + g * 16);
            f32x4 acc1[8];
            #pragma unroll
            for (int mt = 0; mt < 8; ++mt)
                acc1[mt] = __builtin_amdgcn_mfma_f32_16x16x32_bf16(w1f[mt], tf, (f32x4)0.0f, 0, 0, 0);
            #pragma unroll
            for (int ks = 0; ks < 4; ++ks) {
                union { unsigned u[4]; short8 s; } pk;
                pk.u[0] = pk2(swish(acc1[2 * ks][0]),     swish(acc1[2 * ks][1]));
                pk.u[1] = pk2(swish(acc1[2 * ks][2]),     swish(acc1[2 * ks][3]));
                pk.u[2] = pk2(swish(acc1[2 * ks + 1][0]), swish(acc1[2 * ks + 1][1]));
                pk.u[3] = pk2(swish(acc1[2 * ks + 1][2]), swish(acc1[2 * ks + 1][3]));
                b2f[nt][ks] = pk.s;
            }
        }
    }

    // ---- layer 2 + folded layer 3: bias in C-init; per mt2-pair emit h2-frag -> facc ----
    float b3v = (r15 < 9) ? b3[r15] : 0.0f;
    f32x4 facc0 = { b3v, b3v, b3v, b3v };
    f32x4 facc1 = facc0;
    #pragma unroll
    for (int i = 0; i < 4; ++i) {
        unsigned cc0[4], cc1[4];
        #pragma unroll
        for (int h = 0; h < 2; ++h) {
            const int mt2 = 2 * i + h;
            short8 a0 = wsf[512 + (mt2 * 4 + 0) * 64 + lane];
            short8 a1 = wsf[512 + (mt2 * 4 + 1) * 64 + lane];
            short8 a2 = wsf[512 + (mt2 * 4 + 2) * 64 + lane];
            short8 a3 = wsf[512 + (mt2 * 4 + 3) * 64 + lane];
            const f32x4 bias = *(const f32x4*)(b2g + mt2 * 16 + 4 * g);
            #pragma unroll
            for (int nt = 0; nt < 2; ++nt) {
                f32x4 acc = __builtin_amdgcn_mfma_f32_16x16x32_bf16(a0, b2f[nt][0], bias, 0, 0, 0);
                acc = __builtin_amdgcn_mfma_f32_16x16x32_bf16(a1, b2f[nt][1], acc, 0, 0, 0);
                acc = __builtin_amdgcn_mfma_f32_16x16x32_bf16(a2, b2f[nt][2], acc, 0, 0, 0);
                acc = __builtin_amdgcn_mfma_f32_16x16x32_bf16(a3, b2f[nt][3], acc, 0, 0, 0);
                unsigned p0 = pk2(swish(acc[0]), swish(acc[1]));
                unsigned p1 = pk2(swish(acc[2]), swish(acc[3]));
                if (nt == 0) { cc0[2 * h] = p0; cc0[2 * h + 1] = p1; }
                else         { cc1[2 * h] = p0; cc1[2 * h + 1] = p1; }
            }
        }
        short8 b3fi = wsf[2560 + i * 64 + lane];
        union { unsigned u[4]; short8 s; } u0, u1;
        #pragma unroll
        for (int q = 0; q < 4; ++q) { u0.u[q] = cc0[q]; u1.u[q] = cc1[q]; }
        facc0 = __builtin_amdgcn_mfma_f32_16x16x32_bf16(u0.s, b3fi, facc0, 0, 0, 0);
        facc1 = __builtin_amdgcn_mfma_f32_16x16x32_bf16(u1.s, b3fi, facc1, 0, 0, 0);
    }

    // ---- epilogue: f -> f_lds (b3 already in init) ----
    if (r15 < 9) {
        #pragma unroll
        for (int e = 0; e < 4; ++e) {
            f_lds[32 * w + 4 * g + e][r15]      = facc0[e];
            f_lds[32 * w + 16 + 4 * g + e][r15] = facc1[e];
        }
    }
    __syncthreads();

    // ---- gather: 3-tap stencil, boundaries zeroed (378 outputs, strided loop) ----
    for (int o = tid; o < 3 * JOUT; o += 256) {
        int jo = o / 3, c = o - jo * 3;
        int j = j0 + jo;
        if (j < Nn) {
            float val = 0.0f;
            if (j != 0 && j != Nn - 1) {
                int cP = (c == 0) ? 3 : (c == 1) ? 4 : 0;
                int cM = (c == 0) ? 5 : (c == 1) ? 6 : 1;
                int cN = (c == 0) ? 7 : (c == 1) ? 8 : 2;
                if (j <= Nn - 3) val += f_lds[jo + 2][cP];   // i = j
                val += f_lds[jo + 1][cM];                    // i = j-1
                if (j >= 2) val += f_lds[jo][cN];            // i = j-2
            }
            out[((size_t)b * Nn + j) * 3 + c] = val;
        }
    }
}

extern "C" void kernel_launch(void* const* d_in, const int* in_sizes, int n_in,
                              void* d_out, int out_size, void* d_ws, size_t ws_size,
                              hipStream_t stream)
{
    const float* y  = (const float*)d_in[0];
    const float* W1 = (const float*)d_in[1];
    const float* b1 = (const float*)d_in[2];
    const float* W2 = (const float*)d_in[3];
    const float* b2 = (const float*)d_in[4];
    const float* W3 = (const float*)d_in[5];
    const float* b3 = (const float*)d_in[6];
    unsigned short* ws = (unsigned short*)d_ws;   // needs 45056 B
    float* out = (float*)d_out;

    prep_kernel<<<88, 256, 0, stream>>>(W1, b1, W2, W3, ws);
    dim3 grid(NBJ, Bn);
    fused_kernel<<<grid, 256, 0, stream>>>(y, b2, b3, ws, out);
}

// Round 15
// 86.652 us; speedup vs baseline: 1.0055x; 1.0055x over previous
//
#include <hip/hip_runtime.h>
#include <hip/hip_bf16.h>

#define Bn 128
#define Nn 8192
#define Hn 128
#define RPB 128
#define JOUT 126
#define NBJ 66    // ceil(8192/126)

typedef __attribute__((ext_vector_type(8))) short short8;
typedef __attribute__((ext_vector_type(4))) float f32x4;
typedef __attribute__((ext_vector_type(4))) unsigned int u32x4;

__device__ __forceinline__ unsigned short f2bf(float x) {
    union { float f; unsigned u; } v; v.f = x;
    return (unsigned short)((v.u + 0x7fffu + ((v.u >> 16) & 1u)) >> 16);
}
__device__ __forceinline__ float bf2f(unsigned short h) {
    union { unsigned u; float f; } v; v.u = ((unsigned)h) << 16;
    return v.f;
}
__device__ __forceinline__ unsigned short flo(float x) {   // low bf16 correction
    return f2bf(x - bf2f(f2bf(x)));
}
__device__ __forceinline__ float asf(unsigned u) {
    union { unsigned u; float f; } v; v.u = u; return v.f;
}
__device__ __forceinline__ float swish(float x) {
    return x * __builtin_amdgcn_rcpf(1.0f + __expf(-x));
}
// HW packed bf16 convert (RNE): dst.lo=cvt(a), dst.hi=cvt(b).
// hip_bf16.h's __float2bfloat16 is a ~5-op software RNE sequence; no builtin
// exists for v_cvt_pk_bf16_f32 on gfx950 (m240) -> inline asm. (R12 win: -15us)
__device__ __forceinline__ unsigned pk2(float a, float b) {
    unsigned r;
    asm("v_cvt_pk_bf16_f32 %0, %1, %2" : "=v"(r) : "v"(a), "v"(b));
    return r;
}

// ws (unsigned short, 22528 elems = 45056 B):
//  [0      .. 4095 ]  8  A1-frags (W1 hi/lo + b1 folded), frag mt: m=16mt+(l&15)
//  [4096   .. 20479] 32  A2-frags (W2, k-map kappa), frag (mt2*4+ks)
//  [20480  .. 22527]  4  B3-frags (W3, k-map kappa), frag ks
// kappa(ks, p) = 16*(2ks + ((p&7)>>2)) + 4*(p>>3) + (p&3),  p = slot (l>>4)*8+e
__global__ void prep_kernel(const float* __restrict__ W1, const float* __restrict__ b1,
                            const float* __restrict__ W2, const float* __restrict__ W3,
                            unsigned short* __restrict__ ws)
{
    int tid = blockIdx.x * 256 + threadIdx.x;
    if (tid >= 22528) return;
    int f = tid >> 9, r = tid & 511;
    int l = r >> 3, e = r & 7;
    int p = ((l >> 4) << 3) | e;
    int c16 = l & 15;
    unsigned short v = 0;
    if (f < 8) {
        int col = (f << 4) | c16;
        if (p < 9)        v = f2bf(W1[p * Hn + col]);        // pairs t_hi
        else if (p < 18)  v = flo(W1[(p - 9) * Hn + col]);   // pairs t_hi
        else if (p < 27)  v = f2bf(W1[(p - 18) * Hn + col]); // pairs t_lo
        else if (p == 27) v = f2bf(b1[col]);                 // pairs 1.0
        else if (p == 28) v = flo(b1[col]);                  // pairs 1.0
    } else if (f < 40) {
        int mt2 = (f - 8) >> 2, ks = (f - 8) & 3;
        int col = (mt2 << 4) | c16;
        int k = 16 * (2 * ks + ((p & 7) >> 2)) + ((p >> 3) << 2) + (p & 3);
        v = f2bf(W2[k * Hn + col]);
    } else {
        int ks = f - 40;
        int k = 16 * (2 * ks + ((p & 7) >> 2)) + ((p >> 3) << 2) + (p & 3);
        if (c16 < 9) v = f2bf(W3[k * 9 + c16]);
    }
    ws[tid] = v;
}

__global__ __launch_bounds__(256, 5) void fused_kernel(
    const float* __restrict__ y, const float* __restrict__ b2g,
    const float* __restrict__ b3, const unsigned short* __restrict__ ws,
    float* __restrict__ out)
{
    __shared__ __align__(16) char tb[RPB * 80];  // per-row 32-slot bf16 k-vector, stride 80B
    __shared__ float f_lds[RPB][12];

    const int tid = threadIdx.x;
    const int lane = tid & 63;
    const int w = tid >> 6;
    const int b = blockIdx.y;
    const int j0 = blockIdx.x * JOUT;
    const int r15 = lane & 15, g = lane >> 4;

    const short8* wsf = (const short8*)ws;

    // ---- triplet features: 128 threads, one row each -> hi/lo k-vectors in LDS ----
    if (tid < RPB) {
        int i = j0 - 2 + tid;
        i = (i < 0) ? 0 : ((i > Nn - 3) ? (Nn - 3) : i);
        const float* base = y + ((size_t)b * Nn + i) * 6;
        float xp0 = base[0],  xp1 = base[1],  xp2 = base[2];
        float xm0 = base[6],  xm1 = base[7],  xm2 = base[8];
        float xn0 = base[12], xn1 = base[13], xn2 = base[14];
        float off = atan2f(xm1 - xp1, xm0 - xp0);
        float t0 = xp2 - off, t1 = xm2 - off, t2 = xn2 - off;
        unsigned hw0 = pk2(t0, t1);          // (h0,h1)
        unsigned hw1 = pk2(t2, xp0);         // (h2,h3)
        unsigned hw2 = pk2(xp1, xm0);        // (h4,h5)
        unsigned hw3 = pk2(xm1, xn0);        // (h6,h7)
        unsigned hw8 = pk2(xn1, 1.0f);       // (h8, 1.0)
        float r0 = t0  - asf(hw0 << 16), r1 = t1  - asf(hw0 & 0xffff0000u);
        float r2 = t2  - asf(hw1 << 16), r3 = xp0 - asf(hw1 & 0xffff0000u);
        float r4 = xp1 - asf(hw2 << 16), r5 = xm0 - asf(hw2 & 0xffff0000u);
        float r6 = xm1 - asf(hw3 << 16), r7 = xn0 - asf(hw3 & 0xffff0000u);
        float r8 = xn1 - asf(hw8 << 16);
        u32x4 v0 = { hw0, hw1, hw2, hw3 };                                  // slots 0..7
        u32x4 v1 = { (hw0 << 16) | (hw8 & 0xffffu),                         // (h8,h0)
                     __builtin_amdgcn_alignbit(hw1, hw0, 16),               // (h1,h2)
                     __builtin_amdgcn_alignbit(hw2, hw1, 16),               // (h3,h4)
                     __builtin_amdgcn_alignbit(hw3, hw2, 16) };             // (h5,h6)
        u32x4 v2 = { __builtin_amdgcn_alignbit(hw8, hw3, 16),               // (h7,h8)
                     pk2(r0, r1), pk2(r2, r3), pk2(r4, r5) };               // (l0..l5)
        u32x4 v3 = { pk2(r6, r7), pk2(r8, 1.0f), 0x00003F80u, 0u };        // (l6..l8,1,1,0,0)
        char* dst = tb + tid * 80;
        *(u32x4*)(dst)      = v0;
        *(u32x4*)(dst + 16) = v1;
        *(u32x4*)(dst + 32) = v2;
        *(u32x4*)(dst + 48) = v3;
    }
    __syncthreads();

    // ---- layer 1: per row-tile nt, 8 MFMAs (A=W1 frags, B=t k-vec), hi/lo fp32 ----
    short8 b2f[2][4];
    {
        short8 w1f[8];
        #pragma unroll
        for (int mt = 0; mt < 8; ++mt) w1f[mt] = wsf[mt * 64 + lane];
        #pragma unroll
        for (int nt = 0; nt < 2; ++nt) {
            short8 tf = *(const short8*)(tb + (32 * w + 16 * nt + r15) * 80 + g * 16);
            f32x4 acc1[8];
            #pragma unroll
            for (int mt = 0; mt < 8; ++mt)
                acc1[mt] = __builtin_amdgcn_mfma_f32_16x16x32_bf16(w1f[mt], tf, (f32x4)0.0f, 0, 0, 0);
            #pragma unroll
            for (int ks = 0; ks < 4; ++ks) {
                union { unsigned u[4]; short8 s; } pk;
                pk.u[0] = pk2(swish(acc1[2 * ks][0]),     swish(acc1[2 * ks][1]));
                pk.u[1] = pk2(swish(acc1[2 * ks][2]),     swish(acc1[2 * ks][3]));
                pk.u[2] = pk2(swish(acc1[2 * ks + 1][0]), swish(acc1[2 * ks + 1][1]));
                pk.u[3] = pk2(swish(acc1[2 * ks + 1][2]), swish(acc1[2 * ks + 1][3]));
                b2f[nt][ks] = pk.s;
            }
        }
    }

    // ---- layer 2 + folded layer 3: bias in C-init; per mt2-pair emit h2-frag -> facc ----
    float b3v = (r15 < 9) ? b3[r15] : 0.0f;
    f32x4 facc0 = { b3v, b3v, b3v, b3v };
    f32x4 facc1 = facc0;
    #pragma unroll
    for (int i = 0; i < 4; ++i) {
        unsigned cc0[4], cc1[4];
        #pragma unroll
        for (int h = 0; h < 2; ++h) {
            const int mt2 = 2 * i + h;
            short8 a0 = wsf[512 + (mt2 * 4 + 0) * 64 + lane];
            short8 a1 = wsf[512 + (mt2 * 4 + 1) * 64 + lane];
            short8 a2 = wsf[512 + (mt2 * 4 + 2) * 64 + lane];
            short8 a3 = wsf[512 + (mt2 * 4 + 3) * 64 + lane];
            const f32x4 bias = *(const f32x4*)(b2g + mt2 * 16 + 4 * g);
            #pragma unroll
            for (int nt = 0; nt < 2; ++nt) {
                f32x4 acc = __builtin_amdgcn_mfma_f32_16x16x32_bf16(a0, b2f[nt][0], bias, 0, 0, 0);
                acc = __builtin_amdgcn_mfma_f32_16x16x32_bf16(a1, b2f[nt][1], acc, 0, 0, 0);
                acc = __builtin_amdgcn_mfma_f32_16x16x32_bf16(a2, b2f[nt][2], acc, 0, 0, 0);
                acc = __builtin_amdgcn_mfma_f32_16x16x32_bf16(a3, b2f[nt][3], acc, 0, 0, 0);
                unsigned p0 = pk2(swish(acc[0]), swish(acc[1]));
                unsigned p1 = pk2(swish(acc[2]), swish(acc[3]));
                if (nt == 0) { cc0[2 * h] = p0; cc0[2 * h + 1] = p1; }
                else         { cc1[2 * h] = p0; cc1[2 * h + 1] = p1; }
            }
        }
        short8 b3fi = wsf[2560 + i * 64 + lane];
        union { unsigned u[4]; short8 s; } u0, u1;
        #pragma unroll
        for (int q = 0; q < 4; ++q) { u0.u[q] = cc0[q]; u1.u[q] = cc1[q]; }
        facc0 = __builtin_amdgcn_mfma_f32_16x16x32_bf16(u0.s, b3fi, facc0, 0, 0, 0);
        facc1 = __builtin_amdgcn_mfma_f32_16x16x32_bf16(u1.s, b3fi, facc1, 0, 0, 0);
    }

    // ---- epilogue: f -> f_lds (b3 already in init) ----
    if (r15 < 9) {
        #pragma unroll
        for (int e = 0; e < 4; ++e) {
            f_lds[32 * w + 4 * g + e][r15]      = facc0[e];
            f_lds[32 * w + 16 + 4 * g + e][r15] = facc1[e];
        }
    }
    __syncthreads();

    // ---- gather: 3-tap stencil, boundaries zeroed (378 outputs, strided loop) ----
    for (int o = tid; o < 3 * JOUT; o += 256) {
        int jo = o / 3, c = o - jo * 3;
        int j = j0 + jo;
        if (j < Nn) {
            float val = 0.0f;
            if (j != 0 && j != Nn - 1) {
                int cP = (c == 0) ? 3 : (c == 1) ? 4 : 0;
                int cM = (c == 0) ? 5 : (c == 1) ? 6 : 1;
                int cN = (c == 0) ? 7 : (c == 1) ? 8 : 2;
                if (j <= Nn - 3) val += f_lds[jo + 2][cP];   // i = j
                val += f_lds[jo + 1][cM];                    // i = j-1
                if (j >= 2) val += f_lds[jo][cN];            // i = j-2
            }
            out[((size_t)b * Nn + j) * 3 + c] = val;
        }
    }
}

extern "C" void kernel_launch(void* const* d_in, const int* in_sizes, int n_in,
                              void* d_out, int out_size, void* d_ws, size_t ws_size,
                              hipStream_t stream)
{
    const float* y  = (const float*)d_in[0];
    const float* W1 = (const float*)d_in[1];
    const float* b1 = (const float*)d_in[2];
    const float* W2 = (const float*)d_in[3];
    const float* b2 = (const float*)d_in[4];
    const float* W3 = (const float*)d_in[5];
    const float* b3 = (const float*)d_in[6];
    unsigned short* ws = (unsigned short*)d_ws;   // needs 45056 B
    float* out = (float*)d_out;

    prep_kernel<<<88, 256, 0, stream>>>(W1, b1, W2, W3, ws);
    dim3 grid(NBJ, Bn);
    fused_kernel<<<grid, 256, 0, stream>>>(y, b2, b3, ws, out);
}